// Round 1
// baseline (731.470 us; speedup 1.0000x reference)
//
#include <hip/hip_runtime.h>
#include <math.h>

#define NN 50000
#define NE 800000
#define NG 64
#define NEG 0.01f

// ---------- monotone float<->uint encoding for atomicMax on floats ----------
__device__ __forceinline__ unsigned fenc(float f) {
  unsigned b = __float_as_uint(f);
  return (b & 0x80000000u) ? ~b : (b | 0x80000000u);
}
__device__ __forceinline__ float fdec(unsigned k) {
  unsigned b = (k & 0x80000000u) ? (k ^ 0x80000000u) : ~k;
  return __uint_as_float(b);
}

// ---------- degree histogram over dst ----------
__global__ void hist_kernel(const int* __restrict__ dst, int* __restrict__ cnt) {
  int i = blockIdx.x * blockDim.x + threadIdx.x;
  if (i < NE) atomicAdd(&cnt[dst[i]], 1);
}

__global__ void dinv_kernel(const int* __restrict__ cnt, float* __restrict__ dinv) {
  int i = blockIdx.x * blockDim.x + threadIdx.x;
  if (i < NN) dinv[i] = 1.0f / sqrtf((float)(cnt[i] + 1)); // +1 self loop
}

// ---------- single-block exclusive scan (50000 elems, chunk-per-thread) ----------
__global__ __launch_bounds__(1024) void scan_kernel(const int* __restrict__ cnt,
                                                    int* __restrict__ row_start,
                                                    int* __restrict__ cursor) {
  __shared__ int sums[1024];
  const int t = threadIdx.x;
  const int CHUNK = (NN + 1023) / 1024;  // 49
  int i0 = t * CHUNK;
  int i1 = i0 + CHUNK; if (i1 > NN) i1 = NN; if (i0 > NN) i0 = NN;
  int s = 0;
  for (int i = i0; i < i1; ++i) s += cnt[i];
  sums[t] = s;
  __syncthreads();
  for (int ofs = 1; ofs < 1024; ofs <<= 1) {
    int v = (t >= ofs) ? sums[t - ofs] : 0;
    __syncthreads();
    sums[t] += v;
    __syncthreads();
  }
  int run = sums[t] - s;  // exclusive prefix of this thread's chunk
  for (int i = i0; i < i1; ++i) {
    row_start[i] = run; cursor[i] = run;
    run += cnt[i];
  }
  if (t == 1023) row_start[NN] = run;  // == NE
}

// ---------- CSR scatter ----------
__global__ void scatter_kernel(const int* __restrict__ src, const int* __restrict__ dst,
                               int* __restrict__ cursor, int* __restrict__ csr) {
  int i = blockIdx.x * blockDim.x + threadIdx.x;
  if (i < NE) {
    int d = dst[i];
    int pos = atomicAdd(&cursor[d], 1);
    csr[pos] = src[i];
  }
}

// ---------- fp32 tiled GEMM: C[M,N] = A[M,K] @ B[K,N]  (row-major) ----------
// MODE: 0 = raw, 1 = +bias, 2 = +bias leaky, 3 = +bias relu
template <int MODE>
__global__ __launch_bounds__(256) void gemm_tile(const float* __restrict__ A,
                                                 const float* __restrict__ B,
                                                 const float* __restrict__ bias,
                                                 float* __restrict__ C,
                                                 int M, int N, int K) {
  __shared__ float As[16][68];  // [k][m], pad 68 -> 16B-aligned rows, conflict-free reads
  __shared__ float Bs[16][64];  // [k][n]
  const int t = threadIdx.x;
  const int tx = t & 15, ty = t >> 4;
  const int bm = blockIdx.y * 64, bn = blockIdx.x * 64;
  const int ar = t >> 2, ac = (t & 3) * 4;   // A stage: row-in-tile, k-offset
  const int br = t >> 4, bc = (t & 15) * 4;  // B stage: k-row, col-offset
  const int arow = bm + ar;
  const bool aok = arow < M;
  float acc[4][4] = {};
  for (int k0 = 0; k0 < K; k0 += 16) {
    float4 a4 = aok ? *(const float4*)(A + (size_t)arow * K + k0 + ac)
                    : make_float4(0.f, 0.f, 0.f, 0.f);
    float4 b4 = *(const float4*)(B + (size_t)(k0 + br) * N + bn + bc);
    __syncthreads();
    As[ac + 0][ar] = a4.x;
    As[ac + 1][ar] = a4.y;
    As[ac + 2][ar] = a4.z;
    As[ac + 3][ar] = a4.w;
    *(float4*)&Bs[br][bc] = b4;
    __syncthreads();
#pragma unroll
    for (int k = 0; k < 16; ++k) {
      float a[4], b[4];
      *(float4*)a = *(const float4*)&As[k][ty * 4];
      *(float4*)b = *(const float4*)&Bs[k][tx * 4];
#pragma unroll
      for (int i = 0; i < 4; ++i)
#pragma unroll
        for (int j = 0; j < 4; ++j) acc[i][j] = fmaf(a[i], b[j], acc[i][j]);
    }
  }
  float bb[4] = {0.f, 0.f, 0.f, 0.f};
  if (MODE > 0) {
#pragma unroll
    for (int j = 0; j < 4; ++j) bb[j] = bias[bn + tx * 4 + j];
  }
#pragma unroll
  for (int i = 0; i < 4; ++i) {
    int r = bm + ty * 4 + i;
    if (r < M) {
      float vv[4];
#pragma unroll
      for (int j = 0; j < 4; ++j) {
        float v = acc[i][j] + bb[j];
        if (MODE == 2) v = (v >= 0.f) ? v : NEG * v;
        if (MODE == 3) v = fmaxf(v, 0.f);
        vv[j] = v;
      }
      *(float4*)(C + (size_t)r * N + bn + tx * 4) = make_float4(vv[0], vv[1], vv[2], vv[3]);
    }
  }
}

// ---------- CSR aggregation, 64 features: one wave per dst node ----------
// out[n] = dinv[n] * sum_e dinv[src] * h[src] + dinv[n]^2 * h[n]   (+bias,leaky if MODE=1)
template <int MODE>
__global__ __launch_bounds__(256) void agg64_kernel(const float* __restrict__ h,
                                                    const float* __restrict__ dinv,
                                                    const int* __restrict__ row_start,
                                                    const int* __restrict__ csr,
                                                    const float* __restrict__ bias,
                                                    float* __restrict__ out) {
  int wid = (blockIdx.x * 256 + threadIdx.x) >> 6;
  int lane = threadIdx.x & 63;
  if (wid >= NN) return;
  float dn = dinv[wid];
  int e0 = row_start[wid], e1 = row_start[wid + 1];
  float acc = 0.f;
  for (int e = e0; e < e1; ++e) {
    int s = csr[e];
    acc = fmaf(dinv[s], h[(size_t)s * 64 + lane], acc);
  }
  float v = fmaf(dn, acc, dn * dn * h[(size_t)wid * 64 + lane]);
  if (MODE == 1) {
    v += bias[lane];
    v = (v >= 0.f) ? v : NEG * v;
  }
  out[(size_t)wid * 64 + lane] = v;
}

// ---------- CSR aggregation, 128 features (float2 per lane) ----------
__global__ __launch_bounds__(256) void agg128_kernel(const float* __restrict__ h,
                                                     const float* __restrict__ dinv,
                                                     const int* __restrict__ row_start,
                                                     const int* __restrict__ csr,
                                                     float* __restrict__ out) {
  int wid = (blockIdx.x * 256 + threadIdx.x) >> 6;
  int lane = threadIdx.x & 63;
  if (wid >= NN) return;
  const float2* h2 = (const float2*)h;
  float dn = dinv[wid];
  int e0 = row_start[wid], e1 = row_start[wid + 1];
  float ax = 0.f, ay = 0.f;
  for (int e = e0; e < e1; ++e) {
    int s = csr[e];
    float ds = dinv[s];
    float2 hv = h2[(size_t)s * 64 + lane];
    ax = fmaf(ds, hv.x, ax);
    ay = fmaf(ds, hv.y, ay);
  }
  float2 hn = h2[(size_t)wid * 64 + lane];
  float2 o;
  o.x = fmaf(dn, ax, dn * dn * hn.x);
  o.y = fmaf(dn, ay, dn * dn * hn.y);
  ((float2*)out)[(size_t)wid * 64 + lane] = o;
}

// ---------- segment max over sorted batch, 256 feats ----------
#define SEG_CHUNK 125
__global__ __launch_bounds__(256) void segmax_kernel(const float* __restrict__ h,
                                                     const int* __restrict__ batch,
                                                     unsigned* __restrict__ gmax) {
  int t = threadIdx.x;
  int n0 = blockIdx.x * SEG_CHUNK;
  int n1 = n0 + SEG_CHUNK; if (n1 > NN) n1 = NN;
  int cur = batch[n0];
  float m = -INFINITY;
  for (int n = n0; n < n1; ++n) {
    int g = batch[n];
    if (g != cur) {
      atomicMax(&gmax[cur * 256 + t], fenc(m));
      cur = g;
      m = -INFINITY;
    }
    m = fmaxf(m, h[(size_t)n * 256 + t]);
  }
  atomicMax(&gmax[cur * 256 + t], fenc(m));
}

__global__ void decode_kernel(const unsigned* __restrict__ gmax, float* __restrict__ g) {
  int i = blockIdx.x * blockDim.x + threadIdx.x;
  if (i < NG * 256) g[i] = fdec(gmax[i]);
}

// ---------- final 64x4 = [64,512] @ [512,4] + b ----------
__global__ __launch_bounds__(256) void final_kernel(const float* __restrict__ g2,
                                                    const float* __restrict__ W,
                                                    const float* __restrict__ b,
                                                    float* __restrict__ out) {
  __shared__ float red[256][4];
  int m = blockIdx.x, t = threadIdx.x;
  float acc[4] = {0.f, 0.f, 0.f, 0.f};
  for (int k = t; k < 512; k += 256) {
    float gv = g2[m * 512 + k];
#pragma unroll
    for (int n = 0; n < 4; ++n) acc[n] = fmaf(gv, W[k * 4 + n], acc[n]);
  }
#pragma unroll
  for (int n = 0; n < 4; ++n) red[t][n] = acc[n];
  __syncthreads();
  for (int s = 128; s > 0; s >>= 1) {
    if (t < s)
#pragma unroll
      for (int n = 0; n < 4; ++n) red[t][n] += red[t + s][n];
    __syncthreads();
  }
  if (t < 4) out[m * 4 + t] = red[0][t] + b[t];
}

extern "C" void kernel_launch(void* const* d_in, const int* in_sizes, int n_in,
                              void* d_out, int out_size, void* d_ws, size_t ws_size,
                              hipStream_t stream) {
  const float* x   = (const float*)d_in[0];
  const int*   ei  = (const int*)d_in[1];
  const int* batch = (const int*)d_in[2];
  const float* W1  = (const float*)d_in[3];
  const float* b1  = (const float*)d_in[4];
  const float* W2  = (const float*)d_in[5];
  const float* b2  = (const float*)d_in[6];
  const float* W3  = (const float*)d_in[7];
  const float* b3  = (const float*)d_in[8];
  const float* Wc1 = (const float*)d_in[9];
  const float* bc1 = (const float*)d_in[10];
  const float* Wc2 = (const float*)d_in[11];
  const float* bc2 = (const float*)d_in[12];
  const float* Wc3 = (const float*)d_in[13];
  const float* bc3 = (const float*)d_in[14];
  const int* src = ei;
  const int* dst = ei + NE;

  // ---- workspace layout (all starts 256B-aligned) ----
  char* base = (char*)d_ws;
  size_t off = 0;
  auto take = [&](size_t bytes) {
    size_t o = off;
    off += (bytes + 255) & ~(size_t)255;
    return o;
  };
  int*      deg_cnt   = (int*)(base + take((size_t)NN * 4));
  float*    dinv      = (float*)(base + take((size_t)NN * 4));
  int*      row_start = (int*)(base + take((size_t)(NN + 1) * 4));
  int*      cursor    = (int*)(base + take((size_t)NN * 4));
  int*      csr       = (int*)(base + take((size_t)NE * 4));
  unsigned* gmax      = (unsigned*)(base + take((size_t)NG * 256 * 4));
  float*    gdec      = (float*)(base + take((size_t)NG * 256 * 4));
  float*    c1out     = (float*)(base + take((size_t)NG * 1024 * 4));
  float*    c2out     = (float*)(base + take((size_t)NG * 512 * 4));
  // big buffers; keep B64_a,B64_b,B128_a contiguous: out3 (51.2MB) overlays them
  float* B64_a  = (float*)(base + take((size_t)NN * 64 * 4));   // h1, then a2
  float* B64_b  = (float*)(base + take((size_t)NN * 64 * 4));   // out1
  float* B128_a = (float*)(base + take((size_t)NN * 128 * 4));  // out2
  float* B128_b = (float*)(base + take((size_t)NN * 128 * 4));  // a3
  float* out3   = B64_a;  // spans B64_a..B128_a end exactly (12.8+12.8+25.6 = 51.2MB)

  // ---- graph build ----
  hipMemsetAsync(deg_cnt, 0, (size_t)NN * 4, stream);
  hipMemsetAsync(gmax, 0, (size_t)NG * 256 * 4, stream);  // 0 == encoded "below any float"
  hist_kernel<<<(NE + 255) / 256, 256, 0, stream>>>(dst, deg_cnt);
  dinv_kernel<<<(NN + 255) / 256, 256, 0, stream>>>(deg_cnt, dinv);
  scan_kernel<<<1, 1024, 0, stream>>>(deg_cnt, row_start, cursor);
  scatter_kernel<<<(NE + 255) / 256, 256, 0, stream>>>(src, dst, cursor, csr);

  const int gy = (NN + 63) / 64;  // 782

  // ---- conv1: h1 = x@W1 ; out1 = leaky(Ahat(h1)+b1) ----
  gemm_tile<0><<<dim3(1, gy), 256, 0, stream>>>(x, W1, nullptr, B64_a, NN, 64, 128);
  agg64_kernel<1><<<(NN * 64) / 256, 256, 0, stream>>>(B64_a, dinv, row_start, csr, b1, B64_b);

  // ---- conv2: a2 = Ahat(out1) ; out2 = leaky(a2@W2+b2) ----
  agg64_kernel<0><<<(NN * 64) / 256, 256, 0, stream>>>(B64_b, dinv, row_start, csr, nullptr, B64_a);
  gemm_tile<2><<<dim3(2, gy), 256, 0, stream>>>(B64_a, W2, b2, B128_a, NN, 128, 64);

  // ---- conv3: a3 = Ahat(out2) ; out3 = a3@W3+b3 ----
  agg128_kernel<<<(NN * 64) / 256, 256, 0, stream>>>(B128_a, dinv, row_start, csr, B128_b);
  gemm_tile<1><<<dim3(4, gy), 256, 0, stream>>>(B128_b, W3, b3, out3, NN, 256, 128);

  // ---- pooling + MLP ----
  segmax_kernel<<<(NN + SEG_CHUNK - 1) / SEG_CHUNK, 256, 0, stream>>>(out3, batch, gmax);
  decode_kernel<<<(NG * 256 + 255) / 256, 256, 0, stream>>>(gmax, gdec);
  gemm_tile<3><<<dim3(16, 1), 256, 0, stream>>>(gdec, Wc1, bc1, c1out, NG, 1024, 256);
  gemm_tile<3><<<dim3(8, 1), 256, 0, stream>>>(c1out, Wc2, bc2, c2out, NG, 512, 1024);
  final_kernel<<<NG, 256, 0, stream>>>(c2out, Wc3, bc3, (float*)d_out);
}

// Round 3
// 641.363 us; speedup vs baseline: 1.1405x; 1.1405x over previous
//
#include <hip/hip_runtime.h>
#include <math.h>

#define NN 50000
#define NE 800000
#define NG 64
#define NEG 0.01f

// ---------- monotone float<->uint encoding for atomicMax on floats ----------
__device__ __forceinline__ unsigned fenc(float f) {
  unsigned b = __float_as_uint(f);
  return (b & 0x80000000u) ? ~b : (b | 0x80000000u);
}
__device__ __forceinline__ float fdec(unsigned k) {
  unsigned b = (k & 0x80000000u) ? (k ^ 0x80000000u) : ~k;
  return __uint_as_float(b);
}

// ---------- degree histogram over dst ----------
__global__ void hist_kernel(const int* __restrict__ dst, int* __restrict__ cnt) {
  int i = blockIdx.x * blockDim.x + threadIdx.x;
  if (i < NE) atomicAdd(&cnt[dst[i]], 1);
}

__global__ void dinv_kernel(const int* __restrict__ cnt, float* __restrict__ dinv) {
  int i = blockIdx.x * blockDim.x + threadIdx.x;
  if (i < NN) dinv[i] = 1.0f / sqrtf((float)(cnt[i] + 1)); // +1 self loop
}

// ---------- 3-phase parallel exclusive scan over cnt[NN] ----------
#define SCAN_ELE 512
#define SCAN_NB ((NN + SCAN_ELE - 1) / SCAN_ELE)  // 98

__global__ __launch_bounds__(256) void scan_reduce(const int* __restrict__ cnt,
                                                   int* __restrict__ partials) {
  int b = blockIdx.x, t = threadIdx.x;
  int i = b * SCAN_ELE + t * 2;
  int v0 = (i < NN) ? cnt[i] : 0;
  int v1 = (i + 1 < NN) ? cnt[i + 1] : 0;
  __shared__ int red[256];
  red[t] = v0 + v1;
  __syncthreads();
  for (int ofs = 128; ofs > 0; ofs >>= 1) {
    if (t < ofs) red[t] += red[t + ofs];
    __syncthreads();
  }
  if (t == 0) partials[b] = red[0];
}

__global__ void scan_partials(int* __restrict__ partials) {  // in-place exclusive
  __shared__ int s[128];
  int t = threadIdx.x;
  int v = (t < SCAN_NB) ? partials[t] : 0;
  s[t] = v;
  __syncthreads();
  for (int ofs = 1; ofs < 128; ofs <<= 1) {
    int u = (t >= ofs) ? s[t - ofs] : 0;
    __syncthreads();
    s[t] += u;
    __syncthreads();
  }
  if (t < SCAN_NB) partials[t] = s[t] - v;
}

__global__ __launch_bounds__(256) void scan_write(const int* __restrict__ cnt,
                                                  const int* __restrict__ partials,
                                                  int* __restrict__ row_start,
                                                  int* __restrict__ cursor) {
  int b = blockIdx.x, t = threadIdx.x;
  int i = b * SCAN_ELE + t * 2;
  int v0 = (i < NN) ? cnt[i] : 0;
  int v1 = (i + 1 < NN) ? cnt[i + 1] : 0;
  int s = v0 + v1;
  __shared__ int sc[256];
  sc[t] = s;
  __syncthreads();
  for (int ofs = 1; ofs < 256; ofs <<= 1) {  // Hillis-Steele inclusive
    int u = (t >= ofs) ? sc[t - ofs] : 0;
    __syncthreads();
    sc[t] += u;
    __syncthreads();
  }
  int base = partials[b] + sc[t] - s;  // exclusive prefix of elem i
  if (i < NN) { row_start[i] = base; cursor[i] = base; }
  if (i + 1 < NN) { row_start[i + 1] = base + v0; cursor[i + 1] = base + v0; }
  if (b == SCAN_NB - 1 && t == 255) row_start[NN] = partials[b] + sc[255];  // == NE
}

// ---------- CSR scatter ----------
__global__ void scatter_kernel(const int* __restrict__ src, const int* __restrict__ dst,
                               int* __restrict__ cursor, int* __restrict__ csr) {
  int i = blockIdx.x * blockDim.x + threadIdx.x;
  if (i < NE) {
    int d = dst[i];
    int pos = atomicAdd(&cursor[d], 1);
    csr[pos] = src[i];
  }
}

// ---------- fp32 tiled GEMM: C[M,N] = A[M,K] @ B[K,N]  (row-major) ----------
// MODE: 0 = raw, 1 = +bias, 2 = +bias leaky, 3 = +bias relu
template <int MODE>
__global__ __launch_bounds__(256) void gemm_tile(const float* __restrict__ A,
                                                 const float* __restrict__ B,
                                                 const float* __restrict__ bias,
                                                 float* __restrict__ C,
                                                 int M, int N, int K) {
  __shared__ float As[16][68];  // [k][m], pad 68 -> 16B-aligned rows, conflict-free reads
  __shared__ float Bs[16][64];  // [k][n]
  const int t = threadIdx.x;
  const int tx = t & 15, ty = t >> 4;
  const int bm = blockIdx.y * 64, bn = blockIdx.x * 64;
  const int ar = t >> 2, ac = (t & 3) * 4;   // A stage: row-in-tile, k-offset
  const int br = t >> 4, bc = (t & 15) * 4;  // B stage: k-row, col-offset
  const int arow = bm + ar;
  const bool aok = arow < M;
  float acc[4][4] = {};
  for (int k0 = 0; k0 < K; k0 += 16) {
    float4 a4 = aok ? *(const float4*)(A + (size_t)arow * K + k0 + ac)
                    : make_float4(0.f, 0.f, 0.f, 0.f);
    float4 b4 = *(const float4*)(B + (size_t)(k0 + br) * N + bn + bc);
    __syncthreads();
    As[ac + 0][ar] = a4.x;
    As[ac + 1][ar] = a4.y;
    As[ac + 2][ar] = a4.z;
    As[ac + 3][ar] = a4.w;
    *(float4*)&Bs[br][bc] = b4;
    __syncthreads();
#pragma unroll
    for (int k = 0; k < 16; ++k) {
      float a[4], b[4];
      *(float4*)a = *(const float4*)&As[k][ty * 4];
      *(float4*)b = *(const float4*)&Bs[k][tx * 4];
#pragma unroll
      for (int i = 0; i < 4; ++i)
#pragma unroll
        for (int j = 0; j < 4; ++j) acc[i][j] = fmaf(a[i], b[j], acc[i][j]);
    }
  }
  float bb[4] = {0.f, 0.f, 0.f, 0.f};
  if (MODE > 0) {
#pragma unroll
    for (int j = 0; j < 4; ++j) bb[j] = bias[bn + tx * 4 + j];
  }
#pragma unroll
  for (int i = 0; i < 4; ++i) {
    int r = bm + ty * 4 + i;
    if (r < M) {
      float vv[4];
#pragma unroll
      for (int j = 0; j < 4; ++j) {
        float v = acc[i][j] + bb[j];
        if (MODE == 2) v = (v >= 0.f) ? v : NEG * v;
        if (MODE == 3) v = fmaxf(v, 0.f);
        vv[j] = v;
      }
      *(float4*)(C + (size_t)r * N + bn + tx * 4) = make_float4(vv[0], vv[1], vv[2], vv[3]);
    }
  }
}

// ---------- CSR aggregation, 64 features: one wave per dst node ----------
// out[n] = dinv[n] * sum_e dinv[src] * h[src] + dinv[n]^2 * h[n]   (+bias,leaky if MODE=1)
template <int MODE>
__global__ __launch_bounds__(256) void agg64_kernel(const float* __restrict__ h,
                                                    const float* __restrict__ dinv,
                                                    const int* __restrict__ row_start,
                                                    const int* __restrict__ csr,
                                                    const float* __restrict__ bias,
                                                    float* __restrict__ out) {
  int wid = (blockIdx.x * 256 + threadIdx.x) >> 6;
  int lane = threadIdx.x & 63;
  if (wid >= NN) return;
  float dn = dinv[wid];
  int e0 = row_start[wid], e1 = row_start[wid + 1];
  float acc = 0.f;
  for (int e = e0; e < e1; ++e) {
    int s = csr[e];
    acc = fmaf(dinv[s], h[(size_t)s * 64 + lane], acc);
  }
  float v = fmaf(dn, acc, dn * dn * h[(size_t)wid * 64 + lane]);
  if (MODE == 1) {
    v += bias[lane];
    v = (v >= 0.f) ? v : NEG * v;
  }
  out[(size_t)wid * 64 + lane] = v;
}

// ---------- CSR aggregation, 128 features (float2 per lane) ----------
__global__ __launch_bounds__(256) void agg128_kernel(const float* __restrict__ h,
                                                     const float* __restrict__ dinv,
                                                     const int* __restrict__ row_start,
                                                     const int* __restrict__ csr,
                                                     float* __restrict__ out) {
  int wid = (blockIdx.x * 256 + threadIdx.x) >> 6;
  int lane = threadIdx.x & 63;
  if (wid >= NN) return;
  const float2* h2 = (const float2*)h;
  float dn = dinv[wid];
  int e0 = row_start[wid], e1 = row_start[wid + 1];
  float ax = 0.f, ay = 0.f;
  for (int e = e0; e < e1; ++e) {
    int s = csr[e];
    float ds = dinv[s];
    float2 hv = h2[(size_t)s * 64 + lane];
    ax = fmaf(ds, hv.x, ax);
    ay = fmaf(ds, hv.y, ay);
  }
  float2 hn = h2[(size_t)wid * 64 + lane];
  float2 o;
  o.x = fmaf(dn, ax, dn * dn * hn.x);
  o.y = fmaf(dn, ay, dn * dn * hn.y);
  ((float2*)out)[(size_t)wid * 64 + lane] = o;
}

// ---------- segment max over sorted batch, 256 feats ----------
#define SEG_CHUNK 125
__global__ __launch_bounds__(256) void segmax_kernel(const float* __restrict__ h,
                                                     const int* __restrict__ batch,
                                                     unsigned* __restrict__ gmax) {
  int t = threadIdx.x;
  int n0 = blockIdx.x * SEG_CHUNK;
  int n1 = n0 + SEG_CHUNK; if (n1 > NN) n1 = NN;
  int cur = batch[n0];
  float m = -INFINITY;
  for (int n = n0; n < n1; ++n) {
    int g = batch[n];
    if (g != cur) {
      atomicMax(&gmax[cur * 256 + t], fenc(m));
      cur = g;
      m = -INFINITY;
    }
    m = fmaxf(m, h[(size_t)n * 256 + t]);
  }
  atomicMax(&gmax[cur * 256 + t], fenc(m));
}

__global__ void decode_kernel(const unsigned* __restrict__ gmax, float* __restrict__ g) {
  int i = blockIdx.x * blockDim.x + threadIdx.x;
  if (i < NG * 256) g[i] = fdec(gmax[i]);
}

// ---------- final 64x4 = [64,512] @ [512,4] + b ----------
__global__ __launch_bounds__(256) void final_kernel(const float* __restrict__ g2,
                                                    const float* __restrict__ W,
                                                    const float* __restrict__ b,
                                                    float* __restrict__ out) {
  __shared__ float red[256][4];
  int m = blockIdx.x, t = threadIdx.x;
  float acc[4] = {0.f, 0.f, 0.f, 0.f};
  for (int k = t; k < 512; k += 256) {
    float gv = g2[m * 512 + k];
#pragma unroll
    for (int n = 0; n < 4; ++n) acc[n] = fmaf(gv, W[k * 4 + n], acc[n]);
  }
#pragma unroll
  for (int n = 0; n < 4; ++n) red[t][n] = acc[n];
  __syncthreads();
  for (int s = 128; s > 0; s >>= 1) {
    if (t < s)
#pragma unroll
      for (int n = 0; n < 4; ++n) red[t][n] += red[t + s][n];
    __syncthreads();
  }
  if (t < 4) out[m * 4 + t] = red[0][t] + b[t];
}

extern "C" void kernel_launch(void* const* d_in, const int* in_sizes, int n_in,
                              void* d_out, int out_size, void* d_ws, size_t ws_size,
                              hipStream_t stream) {
  const float* x   = (const float*)d_in[0];
  const int*   ei  = (const int*)d_in[1];
  const int* batch = (const int*)d_in[2];
  const float* W1  = (const float*)d_in[3];
  const float* b1  = (const float*)d_in[4];
  const float* W2  = (const float*)d_in[5];
  const float* b2  = (const float*)d_in[6];
  const float* W3  = (const float*)d_in[7];
  const float* b3  = (const float*)d_in[8];
  const float* Wc1 = (const float*)d_in[9];
  const float* bc1 = (const float*)d_in[10];
  const float* Wc2 = (const float*)d_in[11];
  const float* bc2 = (const float*)d_in[12];
  const float* Wc3 = (const float*)d_in[13];
  const float* bc3 = (const float*)d_in[14];
  const int* src = ei;
  const int* dst = ei + NE;

  // ---- workspace layout (all starts 256B-aligned) ----
  char* base = (char*)d_ws;
  size_t off = 0;
  auto take = [&](size_t bytes) {
    size_t o = off;
    off += (bytes + 255) & ~(size_t)255;
    return o;
  };
  int*      deg_cnt   = (int*)(base + take((size_t)NN * 4));
  float*    dinv      = (float*)(base + take((size_t)NN * 4));
  int*      row_start = (int*)(base + take((size_t)(NN + 1) * 4));
  int*      cursor    = (int*)(base + take((size_t)NN * 4));
  int*      partials  = (int*)(base + take((size_t)SCAN_NB * 4));
  int*      csr       = (int*)(base + take((size_t)NE * 4));
  unsigned* gmax      = (unsigned*)(base + take((size_t)NG * 256 * 4));
  float*    gdec      = (float*)(base + take((size_t)NG * 256 * 4));
  float*    c1out     = (float*)(base + take((size_t)NG * 1024 * 4));
  float*    c2out     = (float*)(base + take((size_t)NG * 512 * 4));
  // big buffers; keep B64_a,B64_b,B128_a contiguous: out3 (51.2MB) overlays them
  float* B64_a  = (float*)(base + take((size_t)NN * 64 * 4));   // h1, then a2
  float* B64_b  = (float*)(base + take((size_t)NN * 64 * 4));   // out1
  float* B128_a = (float*)(base + take((size_t)NN * 128 * 4));  // out2
  float* B128_b = (float*)(base + take((size_t)NN * 128 * 4));  // a3
  float* out3   = B64_a;  // spans B64_a..B128_a end exactly (12.8+12.8+25.6 = 51.2MB)

  // ---- graph build ----
  hipMemsetAsync(deg_cnt, 0, (size_t)NN * 4, stream);
  hipMemsetAsync(gmax, 0, (size_t)NG * 256 * 4, stream);  // 0 == encoded "below any float"
  hist_kernel<<<(NE + 255) / 256, 256, 0, stream>>>(dst, deg_cnt);
  dinv_kernel<<<(NN + 255) / 256, 256, 0, stream>>>(deg_cnt, dinv);
  scan_reduce<<<SCAN_NB, 256, 0, stream>>>(deg_cnt, partials);
  scan_partials<<<1, 128, 0, stream>>>(partials);
  scan_write<<<SCAN_NB, 256, 0, stream>>>(deg_cnt, partials, row_start, cursor);
  scatter_kernel<<<(NE + 255) / 256, 256, 0, stream>>>(src, dst, cursor, csr);

  const int gy = (NN + 63) / 64;  // 782

  // ---- conv1: h1 = x@W1 ; out1 = leaky(Ahat(h1)+b1) ----
  gemm_tile<0><<<dim3(1, gy), 256, 0, stream>>>(x, W1, nullptr, B64_a, NN, 64, 128);
  agg64_kernel<1><<<(NN * 64) / 256, 256, 0, stream>>>(B64_a, dinv, row_start, csr, b1, B64_b);

  // ---- conv2: a2 = Ahat(out1) ; out2 = leaky(a2@W2+b2) ----
  agg64_kernel<0><<<(NN * 64) / 256, 256, 0, stream>>>(B64_b, dinv, row_start, csr, nullptr, B64_a);
  gemm_tile<2><<<dim3(2, gy), 256, 0, stream>>>(B64_a, W2, b2, B128_a, NN, 128, 64);

  // ---- conv3: a3 = Ahat(out2) ; out3 = a3@W3+b3 ----
  agg128_kernel<<<(NN * 64) / 256, 256, 0, stream>>>(B128_a, dinv, row_start, csr, B128_b);
  gemm_tile<1><<<dim3(4, gy), 256, 0, stream>>>(B128_b, W3, b3, out3, NN, 256, 128);

  // ---- pooling + MLP ----
  segmax_kernel<<<(NN + SEG_CHUNK - 1) / SEG_CHUNK, 256, 0, stream>>>(out3, batch, gmax);
  decode_kernel<<<(NG * 256 + 255) / 256, 256, 0, stream>>>(gmax, gdec);
  gemm_tile<3><<<dim3(16, 1), 256, 0, stream>>>(gdec, Wc1, bc1, c1out, NG, 1024, 256);
  gemm_tile<3><<<dim3(8, 1), 256, 0, stream>>>(c1out, Wc2, bc2, c2out, NG, 512, 1024);
  final_kernel<<<NG, 256, 0, stream>>>(c2out, Wc3, bc3, (float*)d_out);
}

// Round 6
// 530.694 us; speedup vs baseline: 1.3783x; 1.2085x over previous
//
#include <hip/hip_runtime.h>
#include <math.h>

#define NN 50000
#define NE 800000
#define NG 64
#define NEG 0.01f

// ---------- monotone float<->uint encoding for atomicMax on floats ----------
__device__ __forceinline__ unsigned fenc(float f) {
  unsigned b = __float_as_uint(f);
  return (b & 0x80000000u) ? ~b : (b | 0x80000000u);
}
__device__ __forceinline__ float fdec(unsigned k) {
  unsigned b = (k & 0x80000000u) ? (k ^ 0x80000000u) : ~k;
  return __uint_as_float(b);
}

// ---------- degree histogram over dst ----------
__global__ void hist_kernel(const int* __restrict__ dst, int* __restrict__ cnt) {
  int i = blockIdx.x * blockDim.x + threadIdx.x;
  if (i < NE) atomicAdd(&cnt[dst[i]], 1);
}

// ---------- 3-phase parallel exclusive scan over cnt[NN] (+ fused dinv) ----------
#define SCAN_ELE 512
#define SCAN_NB ((NN + SCAN_ELE - 1) / SCAN_ELE)  // 98

__global__ __launch_bounds__(256) void scan_reduce(const int* __restrict__ cnt,
                                                   int* __restrict__ partials) {
  int b = blockIdx.x, t = threadIdx.x;
  int i = b * SCAN_ELE + t * 2;
  int v0 = (i < NN) ? cnt[i] : 0;
  int v1 = (i + 1 < NN) ? cnt[i + 1] : 0;
  __shared__ int red[256];
  red[t] = v0 + v1;
  __syncthreads();
  for (int ofs = 128; ofs > 0; ofs >>= 1) {
    if (t < ofs) red[t] += red[t + ofs];
    __syncthreads();
  }
  if (t == 0) partials[b] = red[0];
}

__global__ void scan_partials(int* __restrict__ partials) {  // in-place exclusive
  __shared__ int s[128];
  int t = threadIdx.x;
  int v = (t < SCAN_NB) ? partials[t] : 0;
  s[t] = v;
  __syncthreads();
  for (int ofs = 1; ofs < 128; ofs <<= 1) {
    int u = (t >= ofs) ? s[t - ofs] : 0;
    __syncthreads();
    s[t] += u;
    __syncthreads();
  }
  if (t < SCAN_NB) partials[t] = s[t] - v;
}

__global__ __launch_bounds__(256) void scan_write(const int* __restrict__ cnt,
                                                  const int* __restrict__ partials,
                                                  int* __restrict__ row_start,
                                                  int* __restrict__ cursor,
                                                  float* __restrict__ dinv) {
  int b = blockIdx.x, t = threadIdx.x;
  int i = b * SCAN_ELE + t * 2;
  int v0 = (i < NN) ? cnt[i] : 0;
  int v1 = (i + 1 < NN) ? cnt[i + 1] : 0;
  int s = v0 + v1;
  __shared__ int sc[256];
  sc[t] = s;
  __syncthreads();
  for (int ofs = 1; ofs < 256; ofs <<= 1) {  // Hillis-Steele inclusive
    int u = (t >= ofs) ? sc[t - ofs] : 0;
    __syncthreads();
    sc[t] += u;
    __syncthreads();
  }
  int base = partials[b] + sc[t] - s;  // exclusive prefix of elem i
  if (i < NN) {
    row_start[i] = base; cursor[i] = base;
    dinv[i] = 1.0f / sqrtf((float)(v0 + 1));
  }
  if (i + 1 < NN) {
    row_start[i + 1] = base + v0; cursor[i + 1] = base + v0;
    dinv[i + 1] = 1.0f / sqrtf((float)(v1 + 1));
  }
  if (b == SCAN_NB - 1 && t == 255) row_start[NN] = partials[b] + sc[255];  // == NE
}

// ---------- CSR scatter ----------
__global__ void scatter_kernel(const int* __restrict__ src, const int* __restrict__ dst,
                               int* __restrict__ cursor, int* __restrict__ csr) {
  int i = blockIdx.x * blockDim.x + threadIdx.x;
  if (i < NE) {
    int d = dst[i];
    int pos = atomicAdd(&cursor[d], 1);
    csr[pos] = src[i];
  }
}

// ---------- big fp32 GEMM: C[M,N] = A[M,K] @ B[K,N], BM=128, 8x(TN) micro ----------
// MODE: 0 = *dinv[row] (no bias), 1 = leaky(+bias)*dinv[row], 2 = +bias only
template <int BN, int MODE>
__global__ __launch_bounds__(256) void gemm_big(const float* __restrict__ A,
                                                const float* __restrict__ B,
                                                const float* __restrict__ bias,
                                                const float* __restrict__ dinv,
                                                float* __restrict__ C,
                                                int M, int N, int K) {
  constexpr int TN = BN / 16;  // 8 (BN=128) or 4 (BN=64)
  __shared__ float As[16][132];  // [k][m], padded
  __shared__ float Bs[16][BN];   // [k][n]
  const int t = threadIdx.x;
  const int tx = t & 15, ty = t >> 4;
  const int bm = blockIdx.y * 128, bn = blockIdx.x * BN;
  const int ar = t >> 2, ac = (t & 3) * 4;
  const int r0 = bm + ar, r1 = r0 + 64;
  const bool ok0 = r0 < M, ok1 = r1 < M;
  float acc[8][TN] = {};
  for (int k0 = 0; k0 < K; k0 += 16) {
    float4 a0 = ok0 ? *(const float4*)(A + (size_t)r0 * K + k0 + ac) : make_float4(0.f,0.f,0.f,0.f);
    float4 a1 = ok1 ? *(const float4*)(A + (size_t)r1 * K + k0 + ac) : make_float4(0.f,0.f,0.f,0.f);
    float4 bv0, bv1;
    if (BN == 128) {
      const int kr = t >> 5, c4 = (t & 31) * 4;
      bv0 = *(const float4*)(B + (size_t)(k0 + kr) * N + bn + c4);
      bv1 = *(const float4*)(B + (size_t)(k0 + kr + 8) * N + bn + c4);
    } else {
      const int kr = t >> 4, c4 = (t & 15) * 4;
      bv0 = *(const float4*)(B + (size_t)(k0 + kr) * N + bn + c4);
      bv1 = make_float4(0.f,0.f,0.f,0.f);
    }
    __syncthreads();
    As[ac + 0][ar] = a0.x; As[ac + 1][ar] = a0.y; As[ac + 2][ar] = a0.z; As[ac + 3][ar] = a0.w;
    As[ac + 0][ar + 64] = a1.x; As[ac + 1][ar + 64] = a1.y;
    As[ac + 2][ar + 64] = a1.z; As[ac + 3][ar + 64] = a1.w;
    if (BN == 128) {
      *(float4*)&Bs[t >> 5][(t & 31) * 4] = bv0;
      *(float4*)&Bs[(t >> 5) + 8][(t & 31) * 4] = bv1;
    } else {
      *(float4*)&Bs[t >> 4][(t & 15) * 4] = bv0;
    }
    __syncthreads();
#pragma unroll
    for (int k = 0; k < 16; ++k) {
      float a[8], b[TN];
      *(float4*)&a[0] = *(const float4*)&As[k][ty * 8];
      *(float4*)&a[4] = *(const float4*)&As[k][ty * 8 + 4];
      *(float4*)&b[0] = *(const float4*)&Bs[k][tx * 4];
      if (TN == 8) *(float4*)&b[4] = *(const float4*)&Bs[k][64 + tx * 4];
#pragma unroll
      for (int i = 0; i < 8; ++i)
#pragma unroll
        for (int j = 0; j < TN; ++j) acc[i][j] = fmaf(a[i], b[j], acc[i][j]);
    }
  }
  float bb[TN];
#pragma unroll
  for (int j = 0; j < TN; ++j) bb[j] = 0.f;
  if (MODE >= 1) {
#pragma unroll
    for (int j = 0; j < 4; ++j) bb[j] = bias[bn + tx * 4 + j];
    if (TN == 8)
#pragma unroll
      for (int j = 0; j < 4; ++j) bb[4 + j] = bias[bn + 64 + tx * 4 + j];
  }
#pragma unroll
  for (int i = 0; i < 8; ++i) {
    const int r = bm + ty * 8 + i;
    if (r < M) {
      const float dn = (MODE <= 1) ? dinv[r] : 1.0f;
      float v[TN];
#pragma unroll
      for (int j = 0; j < TN; ++j) {
        float u = acc[i][j] + bb[j];
        if (MODE == 1) u = (u >= 0.f) ? u : NEG * u;
        if (MODE <= 1) u = u * dn;
        v[j] = u;
      }
      *(float4*)(C + (size_t)r * N + bn + tx * 4) = make_float4(v[0], v[1], v[2], v[3]);
      if (TN == 8)
        *(float4*)(C + (size_t)r * N + bn + 64 + tx * 4) = make_float4(v[4], v[5], v[6], v[7]);
    }
  }
}

// ---------- small fp32 GEMM (MLP layers): 64x64 tile, 4x4 micro ----------
// MODE: 3 = +bias relu
template <int MODE>
__global__ __launch_bounds__(256) void gemm_tile(const float* __restrict__ A,
                                                 const float* __restrict__ B,
                                                 const float* __restrict__ bias,
                                                 float* __restrict__ C,
                                                 int M, int N, int K) {
  __shared__ float As[16][68];
  __shared__ float Bs[16][64];
  const int t = threadIdx.x;
  const int tx = t & 15, ty = t >> 4;
  const int bm = blockIdx.y * 64, bn = blockIdx.x * 64;
  const int ar = t >> 2, ac = (t & 3) * 4;
  const int br = t >> 4, bc = (t & 15) * 4;
  const int arow = bm + ar;
  const bool aok = arow < M;
  float acc[4][4] = {};
  for (int k0 = 0; k0 < K; k0 += 16) {
    float4 a4 = aok ? *(const float4*)(A + (size_t)arow * K + k0 + ac)
                    : make_float4(0.f, 0.f, 0.f, 0.f);
    float4 b4 = *(const float4*)(B + (size_t)(k0 + br) * N + bn + bc);
    __syncthreads();
    As[ac + 0][ar] = a4.x;
    As[ac + 1][ar] = a4.y;
    As[ac + 2][ar] = a4.z;
    As[ac + 3][ar] = a4.w;
    *(float4*)&Bs[br][bc] = b4;
    __syncthreads();
#pragma unroll
    for (int k = 0; k < 16; ++k) {
      float a[4], b[4];
      *(float4*)a = *(const float4*)&As[k][ty * 4];
      *(float4*)b = *(const float4*)&Bs[k][tx * 4];
#pragma unroll
      for (int i = 0; i < 4; ++i)
#pragma unroll
        for (int j = 0; j < 4; ++j) acc[i][j] = fmaf(a[i], b[j], acc[i][j]);
    }
  }
  float bb[4] = {0.f, 0.f, 0.f, 0.f};
  if (MODE > 0) {
#pragma unroll
    for (int j = 0; j < 4; ++j) bb[j] = bias[bn + tx * 4 + j];
  }
#pragma unroll
  for (int i = 0; i < 4; ++i) {
    int r = bm + ty * 4 + i;
    if (r < M) {
      float vv[4];
#pragma unroll
      for (int j = 0; j < 4; ++j) {
        float v = acc[i][j] + bb[j];
        if (MODE == 3) v = fmaxf(v, 0.f);
        vv[j] = v;
      }
      *(float4*)(C + (size_t)r * N + bn + tx * 4) = make_float4(vv[0], vv[1], vv[2], vv[3]);
    }
  }
}

// ---------- CSR aggregation over pre-scaled hs (= dinv*h), 64 feats ----------
// out = dn*(sum hs[src] + hs[n])  [MODE 0]
// out = dn*leaky(dn*(sum+self) + b)  [MODE 1: conv1 epilogue, stores next hs]
template <int MODE>
__global__ __launch_bounds__(256) void agg64_kernel(const float* __restrict__ hs,
                                                    const float* __restrict__ dinv,
                                                    const int* __restrict__ row_start,
                                                    const int* __restrict__ csr,
                                                    const float* __restrict__ bias,
                                                    float* __restrict__ out) {
  int wid = (blockIdx.x * 256 + threadIdx.x) >> 6;
  int lane = threadIdx.x & 63;
  if (wid >= NN) return;
  int e0 = row_start[wid], e1 = row_start[wid + 1];
  float a0 = 0.f, a1 = 0.f, a2 = 0.f, a3 = 0.f;
  int e = e0;
  for (; e + 4 <= e1; e += 4) {
    int s0 = csr[e], s1 = csr[e + 1], s2 = csr[e + 2], s3 = csr[e + 3];
    a0 += hs[(size_t)s0 * 64 + lane];
    a1 += hs[(size_t)s1 * 64 + lane];
    a2 += hs[(size_t)s2 * 64 + lane];
    a3 += hs[(size_t)s3 * 64 + lane];
  }
  for (; e < e1; ++e) a0 += hs[(size_t)csr[e] * 64 + lane];
  float dn = dinv[wid];
  float acc = (a0 + a1) + (a2 + a3) + hs[(size_t)wid * 64 + lane];
  float v = dn * acc;
  if (MODE == 1) {
    v += bias[lane];
    v = (v >= 0.f) ? v : NEG * v;
    v *= dn;  // pre-scale for next layer's gather
  }
  out[(size_t)wid * 64 + lane] = v;
}

// ---------- CSR aggregation over pre-scaled hs, 128 feats (float2/lane) ----------
__global__ __launch_bounds__(256) void agg128_kernel(const float* __restrict__ hs,
                                                     const float* __restrict__ dinv,
                                                     const int* __restrict__ row_start,
                                                     const int* __restrict__ csr,
                                                     float* __restrict__ out) {
  int wid = (blockIdx.x * 256 + threadIdx.x) >> 6;
  int lane = threadIdx.x & 63;
  if (wid >= NN) return;
  const float2* h2 = (const float2*)hs;
  int e0 = row_start[wid], e1 = row_start[wid + 1];
  float x0 = 0.f, y0 = 0.f, x1 = 0.f, y1 = 0.f, x2 = 0.f, y2 = 0.f, x3 = 0.f, y3 = 0.f;
  int e = e0;
  for (; e + 4 <= e1; e += 4) {
    int s0 = csr[e], s1 = csr[e + 1], s2 = csr[e + 2], s3 = csr[e + 3];
    float2 v0 = h2[(size_t)s0 * 64 + lane];
    float2 v1 = h2[(size_t)s1 * 64 + lane];
    float2 v2 = h2[(size_t)s2 * 64 + lane];
    float2 v3 = h2[(size_t)s3 * 64 + lane];
    x0 += v0.x; y0 += v0.y; x1 += v1.x; y1 += v1.y;
    x2 += v2.x; y2 += v2.y; x3 += v3.x; y3 += v3.y;
  }
  for (; e < e1; ++e) {
    float2 v = h2[(size_t)csr[e] * 64 + lane];
    x0 += v.x; y0 += v.y;
  }
  float2 self = h2[(size_t)wid * 64 + lane];
  float dn = dinv[wid];
  float2 o;
  o.x = dn * ((x0 + x1) + (x2 + x3) + self.x);
  o.y = dn * ((y0 + y1) + (y2 + y3) + self.y);
  ((float2*)out)[(size_t)wid * 64 + lane] = o;
}

// ---------- segment max over sorted batch, 256 feats ----------
#define SEG_CHUNK 125
__global__ __launch_bounds__(256) void segmax_kernel(const float* __restrict__ h,
                                                     const int* __restrict__ batch,
                                                     unsigned* __restrict__ gmax) {
  int t = threadIdx.x;
  int n0 = blockIdx.x * SEG_CHUNK;
  int n1 = n0 + SEG_CHUNK; if (n1 > NN) n1 = NN;
  int cur = batch[n0];
  float m = -INFINITY;
  for (int n = n0; n < n1; ++n) {
    int g = batch[n];
    if (g != cur) {
      atomicMax(&gmax[cur * 256 + t], fenc(m));
      cur = g;
      m = -INFINITY;
    }
    m = fmaxf(m, h[(size_t)n * 256 + t]);
  }
  atomicMax(&gmax[cur * 256 + t], fenc(m));
}

__global__ void decode_kernel(const unsigned* __restrict__ gmax, float* __restrict__ g) {
  int i = blockIdx.x * blockDim.x + threadIdx.x;
  if (i < NG * 256) g[i] = fdec(gmax[i]);
}

// ---------- final 64x4 = [64,512] @ [512,4] + b ----------
__global__ __launch_bounds__(256) void final_kernel(const float* __restrict__ g2,
                                                    const float* __restrict__ W,
                                                    const float* __restrict__ b,
                                                    float* __restrict__ out) {
  __shared__ float red[256][4];
  int m = blockIdx.x, t = threadIdx.x;
  float acc[4] = {0.f, 0.f, 0.f, 0.f};
  for (int k = t; k < 512; k += 256) {
    float gv = g2[m * 512 + k];
#pragma unroll
    for (int n = 0; n < 4; ++n) acc[n] = fmaf(gv, W[k * 4 + n], acc[n]);
  }
#pragma unroll
  for (int n = 0; n < 4; ++n) red[t][n] = acc[n];
  __syncthreads();
  for (int s = 128; s > 0; s >>= 1) {
    if (t < s)
#pragma unroll
      for (int n = 0; n < 4; ++n) red[t][n] += red[t + s][n];
    __syncthreads();
  }
  if (t < 4) out[m * 4 + t] = red[0][t] + b[t];
}

extern "C" void kernel_launch(void* const* d_in, const int* in_sizes, int n_in,
                              void* d_out, int out_size, void* d_ws, size_t ws_size,
                              hipStream_t stream) {
  const float* x   = (const float*)d_in[0];
  const int*   ei  = (const int*)d_in[1];
  const int* batch = (const int*)d_in[2];
  const float* W1  = (const float*)d_in[3];
  const float* b1  = (const float*)d_in[4];
  const float* W2  = (const float*)d_in[5];
  const float* b2  = (const float*)d_in[6];
  const float* W3  = (const float*)d_in[7];
  const float* b3  = (const float*)d_in[8];
  const float* Wc1 = (const float*)d_in[9];
  const float* bc1 = (const float*)d_in[10];
  const float* Wc2 = (const float*)d_in[11];
  const float* bc2 = (const float*)d_in[12];
  const float* Wc3 = (const float*)d_in[13];
  const float* bc3 = (const float*)d_in[14];
  const int* src = ei;
  const int* dst = ei + NE;

  // ---- workspace layout (all starts 256B-aligned) ----
  char* base = (char*)d_ws;
  size_t off = 0;
  auto take = [&](size_t bytes) {
    size_t o = off;
    off += (bytes + 255) & ~(size_t)255;
    return o;
  };
  int*      deg_cnt   = (int*)(base + take((size_t)NN * 4));
  float*    dinv      = (float*)(base + take((size_t)NN * 4));
  int*      row_start = (int*)(base + take((size_t)(NN + 1) * 4));
  int*      cursor    = (int*)(base + take((size_t)NN * 4));
  int*      partials  = (int*)(base + take((size_t)SCAN_NB * 4));
  int*      csr       = (int*)(base + take((size_t)NE * 4));
  unsigned* gmax      = (unsigned*)(base + take((size_t)NG * 256 * 4));
  float*    gdec      = (float*)(base + take((size_t)NG * 256 * 4));
  float*    c1out     = (float*)(base + take((size_t)NG * 1024 * 4));
  float*    c2out     = (float*)(base + take((size_t)NG * 512 * 4));
  // big buffers; keep B64_a,B64_b,B128_a contiguous: out3 (51.2MB) overlays them
  float* B64_a  = (float*)(base + take((size_t)NN * 64 * 4));   // hs0, then a2
  float* B64_b  = (float*)(base + take((size_t)NN * 64 * 4));   // hs1
  float* B128_a = (float*)(base + take((size_t)NN * 128 * 4));  // hs2
  float* B128_b = (float*)(base + take((size_t)NN * 128 * 4));  // a3
  float* out3   = B64_a;  // spans B64_a..B128_a end exactly (12.8+12.8+25.6 = 51.2MB)

  // ---- graph build ----
  hipMemsetAsync(deg_cnt, 0, (size_t)NN * 4, stream);
  hipMemsetAsync(gmax, 0, (size_t)NG * 256 * 4, stream);  // 0 == encoded "below any float"
  hist_kernel<<<(NE + 255) / 256, 256, 0, stream>>>(dst, deg_cnt);
  scan_reduce<<<SCAN_NB, 256, 0, stream>>>(deg_cnt, partials);
  scan_partials<<<1, 128, 0, stream>>>(partials);
  scan_write<<<SCAN_NB, 256, 0, stream>>>(deg_cnt, partials, row_start, cursor, dinv);
  scatter_kernel<<<(NE + 255) / 256, 256, 0, stream>>>(src, dst, cursor, csr);

  const int gy = (NN + 127) / 128;  // 391

  // ---- conv1: hs0 = dinv*(x@W1) ; hs1 = dinv*leaky(Ahat+b1) ----
  gemm_big<64, 0><<<dim3(1, gy), 256, 0, stream>>>(x, W1, nullptr, dinv, B64_a, NN, 64, 128);
  agg64_kernel<1><<<(NN * 64) / 256, 256, 0, stream>>>(B64_a, dinv, row_start, csr, b1, B64_b);

  // ---- conv2: a2 = Ahat(out1) (from hs1) ; hs2 = dinv*leaky(a2@W2+b2) ----
  agg64_kernel<0><<<(NN * 64) / 256, 256, 0, stream>>>(B64_b, dinv, row_start, csr, nullptr, B64_a);
  gemm_big<128, 1><<<dim3(1, gy), 256, 0, stream>>>(B64_a, W2, b2, dinv, B128_a, NN, 128, 64);

  // ---- conv3: a3 = Ahat(out2) (from hs2) ; out3 = a3@W3+b3 ----
  agg128_kernel<<<(NN * 64) / 256, 256, 0, stream>>>(B128_a, dinv, row_start, csr, B128_b);
  gemm_big<128, 2><<<dim3(2, gy), 256, 0, stream>>>(B128_b, W3, b3, nullptr, out3, NN, 256, 128);

  // ---- pooling + MLP ----
  segmax_kernel<<<(NN + SEG_CHUNK - 1) / SEG_CHUNK, 256, 0, stream>>>(out3, batch, gmax);
  decode_kernel<<<(NG * 256 + 255) / 256, 256, 0, stream>>>(gmax, gdec);
  gemm_tile<3><<<dim3(16, 1), 256, 0, stream>>>(gdec, Wc1, bc1, c1out, NG, 1024, 256);
  gemm_tile<3><<<dim3(8, 1), 256, 0, stream>>>(c1out, Wc2, bc2, c2out, NG, 512, 1024);
  final_kernel<<<NG, 256, 0, stream>>>(c2out, Wc3, bc3, (float*)d_out);
}

// Round 11
// 510.864 us; speedup vs baseline: 1.4318x; 1.0388x over previous
//
#include <hip/hip_runtime.h>
#include <math.h>

#define NN 50000
#define NE 800000
#define NG 64
#define NEG 0.01f

// ---------- monotone float<->uint encoding for atomicMax on floats ----------
__device__ __forceinline__ unsigned fenc(float f) {
  unsigned b = __float_as_uint(f);
  return (b & 0x80000000u) ? ~b : (b | 0x80000000u);
}
__device__ __forceinline__ float fdec(unsigned k) {
  unsigned b = (k & 0x80000000u) ? (k ^ 0x80000000u) : ~k;
  return __uint_as_float(b);
}

// ---------- degree histogram over dst ----------
__global__ void hist_kernel(const int* __restrict__ dst, int* __restrict__ cnt) {
  int i = blockIdx.x * blockDim.x + threadIdx.x;
  if (i < NE) atomicAdd(&cnt[dst[i]], 1);
}

// ---------- 3-phase parallel exclusive scan over cnt[NN] (+ fused dinv) ----------
#define SCAN_ELE 512
#define SCAN_NB ((NN + SCAN_ELE - 1) / SCAN_ELE)  // 98

__global__ __launch_bounds__(256) void scan_reduce(const int* __restrict__ cnt,
                                                   int* __restrict__ partials) {
  int b = blockIdx.x, t = threadIdx.x;
  int i = b * SCAN_ELE + t * 2;
  int v0 = (i < NN) ? cnt[i] : 0;
  int v1 = (i + 1 < NN) ? cnt[i + 1] : 0;
  __shared__ int red[256];
  red[t] = v0 + v1;
  __syncthreads();
  for (int ofs = 128; ofs > 0; ofs >>= 1) {
    if (t < ofs) red[t] += red[t + ofs];
    __syncthreads();
  }
  if (t == 0) partials[b] = red[0];
}

__global__ void scan_partials(int* __restrict__ partials) {  // in-place exclusive
  __shared__ int s[128];
  int t = threadIdx.x;
  int v = (t < SCAN_NB) ? partials[t] : 0;
  s[t] = v;
  __syncthreads();
  for (int ofs = 1; ofs < 128; ofs <<= 1) {
    int u = (t >= ofs) ? s[t - ofs] : 0;
    __syncthreads();
    s[t] += u;
    __syncthreads();
  }
  if (t < SCAN_NB) partials[t] = s[t] - v;
}

__global__ __launch_bounds__(256) void scan_write(const int* __restrict__ cnt,
                                                  const int* __restrict__ partials,
                                                  int* __restrict__ row_start,
                                                  int* __restrict__ cursor,
                                                  float* __restrict__ dinv) {
  int b = blockIdx.x, t = threadIdx.x;
  int i = b * SCAN_ELE + t * 2;
  int v0 = (i < NN) ? cnt[i] : 0;
  int v1 = (i + 1 < NN) ? cnt[i + 1] : 0;
  int s = v0 + v1;
  __shared__ int sc[256];
  sc[t] = s;
  __syncthreads();
  for (int ofs = 1; ofs < 256; ofs <<= 1) {  // Hillis-Steele inclusive
    int u = (t >= ofs) ? sc[t - ofs] : 0;
    __syncthreads();
    sc[t] += u;
    __syncthreads();
  }
  int base = partials[b] + sc[t] - s;  // exclusive prefix of elem i
  if (i < NN) {
    row_start[i] = base; cursor[i] = base;
    dinv[i] = 1.0f / sqrtf((float)(v0 + 1));
  }
  if (i + 1 < NN) {
    row_start[i + 1] = base + v0; cursor[i + 1] = base + v0;
    dinv[i + 1] = 1.0f / sqrtf((float)(v1 + 1));
  }
  if (b == SCAN_NB - 1 && t == 255) row_start[NN] = partials[b] + sc[255];  // == NE
}

// ---------- CSR scatter ----------
__global__ void scatter_kernel(const int* __restrict__ src, const int* __restrict__ dst,
                               int* __restrict__ cursor, int* __restrict__ csr) {
  int i = blockIdx.x * blockDim.x + threadIdx.x;
  if (i < NE) {
    int d = dst[i];
    int pos = atomicAdd(&cursor[d], 1);
    csr[pos] = src[i];
  }
}

// ---------- big fp32 GEMM: C[M,N] = A[M,K] @ B[K,N], BM=128, 8x(TN) micro ----------
// MODE: 0 = *dinv[row] (no bias), 1 = leaky(+bias)*dinv[row], 2 = +bias only
template <int BN, int MODE>
__global__ __launch_bounds__(256) void gemm_big(const float* __restrict__ A,
                                                const float* __restrict__ B,
                                                const float* __restrict__ bias,
                                                const float* __restrict__ dinv,
                                                float* __restrict__ C,
                                                int M, int N, int K) {
  constexpr int TN = BN / 16;  // 8 (BN=128) or 4 (BN=64)
  __shared__ float As[16][132];  // [k][m], padded
  __shared__ float Bs[16][BN];   // [k][n]
  const int t = threadIdx.x;
  const int tx = t & 15, ty = t >> 4;
  const int bm = blockIdx.y * 128, bn = blockIdx.x * BN;
  const int ar = t >> 2, ac = (t & 3) * 4;
  const int r0 = bm + ar, r1 = r0 + 64;
  const bool ok0 = r0 < M, ok1 = r1 < M;
  float acc[8][TN] = {};
  for (int k0 = 0; k0 < K; k0 += 16) {
    float4 a0 = ok0 ? *(const float4*)(A + (size_t)r0 * K + k0 + ac) : make_float4(0.f,0.f,0.f,0.f);
    float4 a1 = ok1 ? *(const float4*)(A + (size_t)r1 * K + k0 + ac) : make_float4(0.f,0.f,0.f,0.f);
    float4 bv0, bv1;
    if (BN == 128) {
      const int kr = t >> 5, c4 = (t & 31) * 4;
      bv0 = *(const float4*)(B + (size_t)(k0 + kr) * N + bn + c4);
      bv1 = *(const float4*)(B + (size_t)(k0 + kr + 8) * N + bn + c4);
    } else {
      const int kr = t >> 4, c4 = (t & 15) * 4;
      bv0 = *(const float4*)(B + (size_t)(k0 + kr) * N + bn + c4);
      bv1 = make_float4(0.f,0.f,0.f,0.f);
    }
    __syncthreads();
    As[ac + 0][ar] = a0.x; As[ac + 1][ar] = a0.y; As[ac + 2][ar] = a0.z; As[ac + 3][ar] = a0.w;
    As[ac + 0][ar + 64] = a1.x; As[ac + 1][ar + 64] = a1.y;
    As[ac + 2][ar + 64] = a1.z; As[ac + 3][ar + 64] = a1.w;
    if (BN == 128) {
      *(float4*)&Bs[t >> 5][(t & 31) * 4] = bv0;
      *(float4*)&Bs[(t >> 5) + 8][(t & 31) * 4] = bv1;
    } else {
      *(float4*)&Bs[t >> 4][(t & 15) * 4] = bv0;
    }
    __syncthreads();
#pragma unroll
    for (int k = 0; k < 16; ++k) {
      float a[8], b[TN];
      *(float4*)&a[0] = *(const float4*)&As[k][ty * 8];
      *(float4*)&a[4] = *(const float4*)&As[k][ty * 8 + 4];
      *(float4*)&b[0] = *(const float4*)&Bs[k][tx * 4];
      if (TN == 8) *(float4*)&b[4] = *(const float4*)&Bs[k][64 + tx * 4];
#pragma unroll
      for (int i = 0; i < 8; ++i)
#pragma unroll
        for (int j = 0; j < TN; ++j) acc[i][j] = fmaf(a[i], b[j], acc[i][j]);
    }
  }
  float bb[TN];
#pragma unroll
  for (int j = 0; j < TN; ++j) bb[j] = 0.f;
  if (MODE >= 1) {
#pragma unroll
    for (int j = 0; j < 4; ++j) bb[j] = bias[bn + tx * 4 + j];
    if (TN == 8)
#pragma unroll
      for (int j = 0; j < 4; ++j) bb[4 + j] = bias[bn + 64 + tx * 4 + j];
  }
#pragma unroll
  for (int i = 0; i < 8; ++i) {
    const int r = bm + ty * 8 + i;
    if (r < M) {
      const float dn = (MODE <= 1) ? dinv[r] : 1.0f;
      float v[TN];
#pragma unroll
      for (int j = 0; j < TN; ++j) {
        float u = acc[i][j] + bb[j];
        if (MODE == 1) u = (u >= 0.f) ? u : NEG * u;
        if (MODE <= 1) u = u * dn;
        v[j] = u;
      }
      *(float4*)(C + (size_t)r * N + bn + tx * 4) = make_float4(v[0], v[1], v[2], v[3]);
      if (TN == 8)
        *(float4*)(C + (size_t)r * N + bn + 64 + tx * 4) = make_float4(v[4], v[5], v[6], v[7]);
    }
  }
}

// ---------- CSR aggregation over pre-scaled hs (= dinv*h), 64 feats ----------
template <int MODE>
__global__ __launch_bounds__(256) void agg64_kernel(const float* __restrict__ hs,
                                                    const float* __restrict__ dinv,
                                                    const int* __restrict__ row_start,
                                                    const int* __restrict__ csr,
                                                    const float* __restrict__ bias,
                                                    float* __restrict__ out) {
  int wid = (blockIdx.x * 256 + threadIdx.x) >> 6;
  int lane = threadIdx.x & 63;
  if (wid >= NN) return;
  int e0 = row_start[wid], e1 = row_start[wid + 1];
  float a0 = 0.f, a1 = 0.f, a2 = 0.f, a3 = 0.f;
  int e = e0;
  for (; e + 4 <= e1; e += 4) {
    int s0 = csr[e], s1 = csr[e + 1], s2 = csr[e + 2], s3 = csr[e + 3];
    a0 += hs[(size_t)s0 * 64 + lane];
    a1 += hs[(size_t)s1 * 64 + lane];
    a2 += hs[(size_t)s2 * 64 + lane];
    a3 += hs[(size_t)s3 * 64 + lane];
  }
  for (; e < e1; ++e) a0 += hs[(size_t)csr[e] * 64 + lane];
  float dn = dinv[wid];
  float acc = (a0 + a1) + (a2 + a3) + hs[(size_t)wid * 64 + lane];
  float v = dn * acc;
  if (MODE == 1) {
    v += bias[lane];
    v = (v >= 0.f) ? v : NEG * v;
    v *= dn;  // pre-scale for next layer's gather
  }
  out[(size_t)wid * 64 + lane] = v;
}

// ---------- CSR aggregation over pre-scaled hs, 128 feats (float2/lane) ----------
__global__ __launch_bounds__(256) void agg128_kernel(const float* __restrict__ hs,
                                                     const float* __restrict__ dinv,
                                                     const int* __restrict__ row_start,
                                                     const int* __restrict__ csr,
                                                     float* __restrict__ out) {
  int wid = (blockIdx.x * 256 + threadIdx.x) >> 6;
  int lane = threadIdx.x & 63;
  if (wid >= NN) return;
  const float2* h2 = (const float2*)hs;
  int e0 = row_start[wid], e1 = row_start[wid + 1];
  float x0 = 0.f, y0 = 0.f, x1 = 0.f, y1 = 0.f, x2 = 0.f, y2 = 0.f, x3 = 0.f, y3 = 0.f;
  int e = e0;
  for (; e + 4 <= e1; e += 4) {
    int s0 = csr[e], s1 = csr[e + 1], s2 = csr[e + 2], s3 = csr[e + 3];
    float2 v0 = h2[(size_t)s0 * 64 + lane];
    float2 v1 = h2[(size_t)s1 * 64 + lane];
    float2 v2 = h2[(size_t)s2 * 64 + lane];
    float2 v3 = h2[(size_t)s3 * 64 + lane];
    x0 += v0.x; y0 += v0.y; x1 += v1.x; y1 += v1.y;
    x2 += v2.x; y2 += v2.y; x3 += v3.x; y3 += v3.y;
  }
  for (; e < e1; ++e) {
    float2 v = h2[(size_t)csr[e] * 64 + lane];
    x0 += v.x; y0 += v.y;
  }
  float2 self = h2[(size_t)wid * 64 + lane];
  float dn = dinv[wid];
  float2 o;
  o.x = dn * ((x0 + x1) + (x2 + x3) + self.x);
  o.y = dn * ((y0 + y1) + (y2 + y3) + self.y);
  ((float2*)out)[(size_t)wid * 64 + lane] = o;
}

// ---------- segment max over sorted batch, 256 feats ----------
#define SEG_CHUNK 125
__global__ __launch_bounds__(256) void segmax_kernel(const float* __restrict__ h,
                                                     const int* __restrict__ batch,
                                                     unsigned* __restrict__ gmax) {
  int t = threadIdx.x;
  int n0 = blockIdx.x * SEG_CHUNK;
  int n1 = n0 + SEG_CHUNK; if (n1 > NN) n1 = NN;
  int cur = batch[n0];
  float m = -INFINITY;
  for (int n = n0; n < n1; ++n) {
    int g = batch[n];
    if (g != cur) {
      atomicMax(&gmax[cur * 256 + t], fenc(m));
      cur = g;
      m = -INFINITY;
    }
    m = fmaxf(m, h[(size_t)n * 256 + t]);
  }
  atomicMax(&gmax[cur * 256 + t], fenc(m));
}

// ---------- fused MLP: one block per graph. decode -> 256->1024->512->4 ----------
__global__ __launch_bounds__(256) void mlp_kernel(const unsigned* __restrict__ gmax,
                                                  const float* __restrict__ Wc1,
                                                  const float* __restrict__ bc1,
                                                  const float* __restrict__ Wc2,
                                                  const float* __restrict__ bc2,
                                                  const float* __restrict__ Wc3,
                                                  const float* __restrict__ bc3,
                                                  float* __restrict__ out) {
  __shared__ float g0[256];
  __shared__ float h1[1024];
  __shared__ float h2[512];
  __shared__ float red[256][4];
  const int b = blockIdx.x, t = threadIdx.x;

  g0[t] = fdec(gmax[b * 256 + t]);
  __syncthreads();

  // layer 1: 256 -> 1024, thread t owns cols 4t..4t+3 (one float4 weight load per k)
  {
    float4 acc = *(const float4*)(bc1 + 4 * t);
#pragma unroll 8
    for (int k = 0; k < 256; ++k) {
      float gv = g0[k];
      float4 w = *(const float4*)(Wc1 + (size_t)k * 1024 + 4 * t);
      acc.x = fmaf(gv, w.x, acc.x);
      acc.y = fmaf(gv, w.y, acc.y);
      acc.z = fmaf(gv, w.z, acc.z);
      acc.w = fmaf(gv, w.w, acc.w);
    }
    h1[4 * t + 0] = fmaxf(acc.x, 0.f);
    h1[4 * t + 1] = fmaxf(acc.y, 0.f);
    h1[4 * t + 2] = fmaxf(acc.z, 0.f);
    h1[4 * t + 3] = fmaxf(acc.w, 0.f);
  }
  __syncthreads();

  // layer 2: 1024 -> 512, thread t owns cols 2t..2t+1 (one float2 load per k)
  {
    float2 acc = *(const float2*)(bc2 + 2 * t);
#pragma unroll 8
    for (int k = 0; k < 1024; ++k) {
      float hv = h1[k];
      float2 w = *(const float2*)(Wc2 + (size_t)k * 512 + 2 * t);
      acc.x = fmaf(hv, w.x, acc.x);
      acc.y = fmaf(hv, w.y, acc.y);
    }
    h2[2 * t + 0] = fmaxf(acc.x, 0.f);
    h2[2 * t + 1] = fmaxf(acc.y, 0.f);
  }
  __syncthreads();

  // layer 3: 512 -> 4, block reduce
  float acc[4] = {0.f, 0.f, 0.f, 0.f};
  for (int k = t; k < 512; k += 256) {
    float hv = h2[k];
#pragma unroll
    for (int n = 0; n < 4; ++n) acc[n] = fmaf(hv, Wc3[k * 4 + n], acc[n]);
  }
#pragma unroll
  for (int n = 0; n < 4; ++n) red[t][n] = acc[n];
  __syncthreads();
  for (int s = 128; s > 0; s >>= 1) {
    if (t < s)
#pragma unroll
      for (int n = 0; n < 4; ++n) red[t][n] += red[t + s][n];
    __syncthreads();
  }
  if (t < 4) out[b * 4 + t] = red[0][t] + bc3[t];
}

extern "C" void kernel_launch(void* const* d_in, const int* in_sizes, int n_in,
                              void* d_out, int out_size, void* d_ws, size_t ws_size,
                              hipStream_t stream) {
  const float* x   = (const float*)d_in[0];
  const int*   ei  = (const int*)d_in[1];
  const int* batch = (const int*)d_in[2];
  const float* W1  = (const float*)d_in[3];
  const float* b1  = (const float*)d_in[4];
  const float* W2  = (const float*)d_in[5];
  const float* b2  = (const float*)d_in[6];
  const float* W3  = (const float*)d_in[7];
  const float* b3  = (const float*)d_in[8];
  const float* Wc1 = (const float*)d_in[9];
  const float* bc1 = (const float*)d_in[10];
  const float* Wc2 = (const float*)d_in[11];
  const float* bc2 = (const float*)d_in[12];
  const float* Wc3 = (const float*)d_in[13];
  const float* bc3 = (const float*)d_in[14];
  const int* src = ei;
  const int* dst = ei + NE;

  // ---- workspace layout (all starts 256B-aligned) ----
  char* base = (char*)d_ws;
  size_t off = 0;
  auto take = [&](size_t bytes) {
    size_t o = off;
    off += (bytes + 255) & ~(size_t)255;
    return o;
  };
  int*      deg_cnt   = (int*)(base + take((size_t)NN * 4));
  float*    dinv      = (float*)(base + take((size_t)NN * 4));
  int*      row_start = (int*)(base + take((size_t)(NN + 1) * 4));
  int*      cursor    = (int*)(base + take((size_t)NN * 4));
  int*      partials  = (int*)(base + take((size_t)SCAN_NB * 4));
  int*      csr       = (int*)(base + take((size_t)NE * 4));
  unsigned* gmax      = (unsigned*)(base + take((size_t)NG * 256 * 4));
  // big buffers; keep B64_a,B64_b,B128_a contiguous: out3 (51.2MB) overlays them
  float* B64_a  = (float*)(base + take((size_t)NN * 64 * 4));   // hs0, then a2
  float* B64_b  = (float*)(base + take((size_t)NN * 64 * 4));   // hs1
  float* B128_a = (float*)(base + take((size_t)NN * 128 * 4));  // hs2
  float* B128_b = (float*)(base + take((size_t)NN * 128 * 4));  // a3
  float* out3   = B64_a;  // spans B64_a..B128_a end exactly (12.8+12.8+25.6 = 51.2MB)

  // ---- graph build ----
  hipMemsetAsync(deg_cnt, 0, (size_t)NN * 4, stream);
  hipMemsetAsync(gmax, 0, (size_t)NG * 256 * 4, stream);  // 0 == encoded "below any float"
  hist_kernel<<<(NE + 255) / 256, 256, 0, stream>>>(dst, deg_cnt);
  scan_reduce<<<SCAN_NB, 256, 0, stream>>>(deg_cnt, partials);
  scan_partials<<<1, 128, 0, stream>>>(partials);
  scan_write<<<SCAN_NB, 256, 0, stream>>>(deg_cnt, partials, row_start, cursor, dinv);
  scatter_kernel<<<(NE + 255) / 256, 256, 0, stream>>>(src, dst, cursor, csr);

  const int gy = (NN + 127) / 128;  // 391

  // ---- conv1: hs0 = dinv*(x@W1) ; hs1 = dinv*leaky(Ahat+b1) ----
  gemm_big<64, 0><<<dim3(1, gy), 256, 0, stream>>>(x, W1, nullptr, dinv, B64_a, NN, 64, 128);
  agg64_kernel<1><<<(NN * 64) / 256, 256, 0, stream>>>(B64_a, dinv, row_start, csr, b1, B64_b);

  // ---- conv2: a2 = Ahat(out1) (from hs1) ; hs2 = dinv*leaky(a2@W2+b2) ----
  agg64_kernel<0><<<(NN * 64) / 256, 256, 0, stream>>>(B64_b, dinv, row_start, csr, nullptr, B64_a);
  gemm_big<128, 1><<<dim3(1, gy), 256, 0, stream>>>(B64_a, W2, b2, dinv, B128_a, NN, 128, 64);

  // ---- conv3: a3 = Ahat(out2) (from hs2) ; out3 = a3@W3+b3 ----
  agg128_kernel<<<(NN * 64) / 256, 256, 0, stream>>>(B128_a, dinv, row_start, csr, B128_b);
  gemm_big<128, 2><<<dim3(2, gy), 256, 0, stream>>>(B128_b, W3, b3, nullptr, out3, NN, 256, 128);

  // ---- pooling + fused MLP ----
  segmax_kernel<<<(NN + SEG_CHUNK - 1) / SEG_CHUNK, 256, 0, stream>>>(out3, batch, gmax);
  mlp_kernel<<<NG, 256, 0, stream>>>(gmax, Wc1, bc1, Wc2, bc2, Wc3, bc3, (float*)d_out);
}

// Round 13
// 475.613 us; speedup vs baseline: 1.5380x; 1.0741x over previous
//
#include <hip/hip_runtime.h>
#include <math.h>

#define NN 50000
#define NE 800000
#define NG 64
#define NEG 0.01f

// ---------- monotone float<->uint encoding for atomicMax on floats ----------
__device__ __forceinline__ unsigned fenc(float f) {
  unsigned b = __float_as_uint(f);
  return (b & 0x80000000u) ? ~b : (b | 0x80000000u);
}
__device__ __forceinline__ float fdec(unsigned k) {
  unsigned b = (k & 0x80000000u) ? (k ^ 0x80000000u) : ~k;
  return __uint_as_float(b);
}

// ---------- degree histogram over dst ----------
__global__ void hist_kernel(const int* __restrict__ dst, int* __restrict__ cnt) {
  int i = blockIdx.x * blockDim.x + threadIdx.x;
  if (i < NE) atomicAdd(&cnt[dst[i]], 1);
}

// ---------- 3-phase parallel exclusive scan over cnt[NN] (+ fused dinv) ----------
#define SCAN_ELE 512
#define SCAN_NB ((NN + SCAN_ELE - 1) / SCAN_ELE)  // 98

__global__ __launch_bounds__(256) void scan_reduce(const int* __restrict__ cnt,
                                                   int* __restrict__ partials) {
  int b = blockIdx.x, t = threadIdx.x;
  int i = b * SCAN_ELE + t * 2;
  int v0 = (i < NN) ? cnt[i] : 0;
  int v1 = (i + 1 < NN) ? cnt[i + 1] : 0;
  __shared__ int red[256];
  red[t] = v0 + v1;
  __syncthreads();
  for (int ofs = 128; ofs > 0; ofs >>= 1) {
    if (t < ofs) red[t] += red[t + ofs];
    __syncthreads();
  }
  if (t == 0) partials[b] = red[0];
}

__global__ void scan_partials(int* __restrict__ partials) {  // in-place exclusive
  __shared__ int s[128];
  int t = threadIdx.x;
  int v = (t < SCAN_NB) ? partials[t] : 0;
  s[t] = v;
  __syncthreads();
  for (int ofs = 1; ofs < 128; ofs <<= 1) {
    int u = (t >= ofs) ? s[t - ofs] : 0;
    __syncthreads();
    s[t] += u;
    __syncthreads();
  }
  if (t < SCAN_NB) partials[t] = s[t] - v;
}

__global__ __launch_bounds__(256) void scan_write(const int* __restrict__ cnt,
                                                  const int* __restrict__ partials,
                                                  int* __restrict__ row_start,
                                                  int* __restrict__ cursor,
                                                  float* __restrict__ dinv) {
  int b = blockIdx.x, t = threadIdx.x;
  int i = b * SCAN_ELE + t * 2;
  int v0 = (i < NN) ? cnt[i] : 0;
  int v1 = (i + 1 < NN) ? cnt[i + 1] : 0;
  int s = v0 + v1;
  __shared__ int sc[256];
  sc[t] = s;
  __syncthreads();
  for (int ofs = 1; ofs < 256; ofs <<= 1) {  // Hillis-Steele inclusive
    int u = (t >= ofs) ? sc[t - ofs] : 0;
    __syncthreads();
    sc[t] += u;
    __syncthreads();
  }
  int base = partials[b] + sc[t] - s;  // exclusive prefix of elem i
  if (i < NN) {
    row_start[i] = base; cursor[i] = base;
    dinv[i] = 1.0f / sqrtf((float)(v0 + 1));
  }
  if (i + 1 < NN) {
    row_start[i + 1] = base + v0; cursor[i + 1] = base + v0;
    dinv[i + 1] = 1.0f / sqrtf((float)(v1 + 1));
  }
  if (b == SCAN_NB - 1 && t == 255) row_start[NN] = partials[b] + sc[255];  // == NE
}

// ---------- CSR scatter ----------
__global__ void scatter_kernel(const int* __restrict__ src, const int* __restrict__ dst,
                               int* __restrict__ cursor, int* __restrict__ csr) {
  int i = blockIdx.x * blockDim.x + threadIdx.x;
  if (i < NE) {
    int d = dst[i];
    int pos = atomicAdd(&cursor[d], 1);
    csr[pos] = src[i];
  }
}

// ---------- big fp32 GEMM: C[M,N] = A[M,K] @ B[K,N], BM=128, 8x(TN) micro ----------
// MODE: 0 = *dinv[row] (no bias), 1 = leaky(+bias)*dinv[row], 2 = +bias only
template <int BN, int MODE>
__global__ __launch_bounds__(256) void gemm_big(const float* __restrict__ A,
                                                const float* __restrict__ B,
                                                const float* __restrict__ bias,
                                                const float* __restrict__ dinv,
                                                float* __restrict__ C,
                                                int M, int N, int K) {
  constexpr int TN = BN / 16;  // 8 (BN=128) or 4 (BN=64)
  __shared__ float As[16][132];  // [k][m], padded
  __shared__ float Bs[16][BN];   // [k][n]
  const int t = threadIdx.x;
  const int tx = t & 15, ty = t >> 4;
  const int bm = blockIdx.y * 128, bn = blockIdx.x * BN;
  const int ar = t >> 2, ac = (t & 3) * 4;
  const int r0 = bm + ar, r1 = r0 + 64;
  const bool ok0 = r0 < M, ok1 = r1 < M;
  float acc[8][TN] = {};
  for (int k0 = 0; k0 < K; k0 += 16) {
    float4 a0 = ok0 ? *(const float4*)(A + (size_t)r0 * K + k0 + ac) : make_float4(0.f,0.f,0.f,0.f);
    float4 a1 = ok1 ? *(const float4*)(A + (size_t)r1 * K + k0 + ac) : make_float4(0.f,0.f,0.f,0.f);
    float4 bv0, bv1;
    if (BN == 128) {
      const int kr = t >> 5, c4 = (t & 31) * 4;
      bv0 = *(const float4*)(B + (size_t)(k0 + kr) * N + bn + c4);
      bv1 = *(const float4*)(B + (size_t)(k0 + kr + 8) * N + bn + c4);
    } else {
      const int kr = t >> 4, c4 = (t & 15) * 4;
      bv0 = *(const float4*)(B + (size_t)(k0 + kr) * N + bn + c4);
      bv1 = make_float4(0.f,0.f,0.f,0.f);
    }
    __syncthreads();
    As[ac + 0][ar] = a0.x; As[ac + 1][ar] = a0.y; As[ac + 2][ar] = a0.z; As[ac + 3][ar] = a0.w;
    As[ac + 0][ar + 64] = a1.x; As[ac + 1][ar + 64] = a1.y;
    As[ac + 2][ar + 64] = a1.z; As[ac + 3][ar + 64] = a1.w;
    if (BN == 128) {
      *(float4*)&Bs[t >> 5][(t & 31) * 4] = bv0;
      *(float4*)&Bs[(t >> 5) + 8][(t & 31) * 4] = bv1;
    } else {
      *(float4*)&Bs[t >> 4][(t & 15) * 4] = bv0;
    }
    __syncthreads();
#pragma unroll
    for (int k = 0; k < 16; ++k) {
      float a[8], b[TN];
      *(float4*)&a[0] = *(const float4*)&As[k][ty * 8];
      *(float4*)&a[4] = *(const float4*)&As[k][ty * 8 + 4];
      *(float4*)&b[0] = *(const float4*)&Bs[k][tx * 4];
      if (TN == 8) *(float4*)&b[4] = *(const float4*)&Bs[k][64 + tx * 4];
#pragma unroll
      for (int i = 0; i < 8; ++i)
#pragma unroll
        for (int j = 0; j < TN; ++j) acc[i][j] = fmaf(a[i], b[j], acc[i][j]);
    }
  }
  float bb[TN];
#pragma unroll
  for (int j = 0; j < TN; ++j) bb[j] = 0.f;
  if (MODE >= 1) {
#pragma unroll
    for (int j = 0; j < 4; ++j) bb[j] = bias[bn + tx * 4 + j];
    if (TN == 8)
#pragma unroll
      for (int j = 0; j < 4; ++j) bb[4 + j] = bias[bn + 64 + tx * 4 + j];
  }
#pragma unroll
  for (int i = 0; i < 8; ++i) {
    const int r = bm + ty * 8 + i;
    if (r < M) {
      const float dn = (MODE <= 1) ? dinv[r] : 1.0f;
      float v[TN];
#pragma unroll
      for (int j = 0; j < TN; ++j) {
        float u = acc[i][j] + bb[j];
        if (MODE == 1) u = (u >= 0.f) ? u : NEG * u;
        if (MODE <= 1) u = u * dn;
        v[j] = u;
      }
      *(float4*)(C + (size_t)r * N + bn + tx * 4) = make_float4(v[0], v[1], v[2], v[3]);
      if (TN == 8)
        *(float4*)(C + (size_t)r * N + bn + 64 + tx * 4) = make_float4(v[4], v[5], v[6], v[7]);
    }
  }
}

// ---------- CSR aggregation over pre-scaled hs (= dinv*h), 64 feats ----------
template <int MODE>
__global__ __launch_bounds__(256) void agg64_kernel(const float* __restrict__ hs,
                                                    const float* __restrict__ dinv,
                                                    const int* __restrict__ row_start,
                                                    const int* __restrict__ csr,
                                                    const float* __restrict__ bias,
                                                    float* __restrict__ out) {
  int wid = (blockIdx.x * 256 + threadIdx.x) >> 6;
  int lane = threadIdx.x & 63;
  if (wid >= NN) return;
  int e0 = row_start[wid], e1 = row_start[wid + 1];
  float a0 = 0.f, a1 = 0.f, a2 = 0.f, a3 = 0.f;
  int e = e0;
  for (; e + 4 <= e1; e += 4) {
    int s0 = csr[e], s1 = csr[e + 1], s2 = csr[e + 2], s3 = csr[e + 3];
    a0 += hs[(size_t)s0 * 64 + lane];
    a1 += hs[(size_t)s1 * 64 + lane];
    a2 += hs[(size_t)s2 * 64 + lane];
    a3 += hs[(size_t)s3 * 64 + lane];
  }
  for (; e < e1; ++e) a0 += hs[(size_t)csr[e] * 64 + lane];
  float dn = dinv[wid];
  float acc = (a0 + a1) + (a2 + a3) + hs[(size_t)wid * 64 + lane];
  float v = dn * acc;
  if (MODE == 1) {
    v += bias[lane];
    v = (v >= 0.f) ? v : NEG * v;
    v *= dn;  // pre-scale for next layer's gather
  }
  out[(size_t)wid * 64 + lane] = v;
}

// ---------- CSR aggregation over pre-scaled hs, 128 feats (float2/lane) ----------
__global__ __launch_bounds__(256) void agg128_kernel(const float* __restrict__ hs,
                                                     const float* __restrict__ dinv,
                                                     const int* __restrict__ row_start,
                                                     const int* __restrict__ csr,
                                                     float* __restrict__ out) {
  int wid = (blockIdx.x * 256 + threadIdx.x) >> 6;
  int lane = threadIdx.x & 63;
  if (wid >= NN) return;
  const float2* h2 = (const float2*)hs;
  int e0 = row_start[wid], e1 = row_start[wid + 1];
  float x0 = 0.f, y0 = 0.f, x1 = 0.f, y1 = 0.f, x2 = 0.f, y2 = 0.f, x3 = 0.f, y3 = 0.f;
  int e = e0;
  for (; e + 4 <= e1; e += 4) {
    int s0 = csr[e], s1 = csr[e + 1], s2 = csr[e + 2], s3 = csr[e + 3];
    float2 v0 = h2[(size_t)s0 * 64 + lane];
    float2 v1 = h2[(size_t)s1 * 64 + lane];
    float2 v2 = h2[(size_t)s2 * 64 + lane];
    float2 v3 = h2[(size_t)s3 * 64 + lane];
    x0 += v0.x; y0 += v0.y; x1 += v1.x; y1 += v1.y;
    x2 += v2.x; y2 += v2.y; x3 += v3.x; y3 += v3.y;
  }
  for (; e < e1; ++e) {
    float2 v = h2[(size_t)csr[e] * 64 + lane];
    x0 += v.x; y0 += v.y;
  }
  float2 self = h2[(size_t)wid * 64 + lane];
  float dn = dinv[wid];
  float2 o;
  o.x = dn * ((x0 + x1) + (x2 + x3) + self.x);
  o.y = dn * ((y0 + y1) + (y2 + y3) + self.y);
  ((float2*)out)[(size_t)wid * 64 + lane] = o;
}

// ---------- segment max over sorted batch, 256 feats ----------
#define SEG_CHUNK 125
__global__ __launch_bounds__(256) void segmax_kernel(const float* __restrict__ h,
                                                     const int* __restrict__ batch,
                                                     unsigned* __restrict__ gmax) {
  int t = threadIdx.x;
  int n0 = blockIdx.x * SEG_CHUNK;
  int n1 = n0 + SEG_CHUNK; if (n1 > NN) n1 = NN;
  int cur = batch[n0];
  float m = -INFINITY;
  for (int n = n0; n < n1; ++n) {
    int g = batch[n];
    if (g != cur) {
      atomicMax(&gmax[cur * 256 + t], fenc(m));
      cur = g;
      m = -INFINITY;
    }
    m = fmaxf(m, h[(size_t)n * 256 + t]);
  }
  atomicMax(&gmax[cur * 256 + t], fenc(m));
}

// ---------- MLP layer 1: c1[64][1024] = relu(g@Wc1+b). 256 blocks ----------
__global__ __launch_bounds__(256) void mlp_l1(const unsigned* __restrict__ gmax,
                                              const float* __restrict__ Wc1,
                                              const float* __restrict__ bc1,
                                              float* __restrict__ c1) {
  const int g = blockIdx.x >> 2;                 // graph 0..63
  const int c = (blockIdx.x & 3) * 256 + threadIdx.x;  // col 0..1023
  __shared__ float g0[256];
  g0[threadIdx.x] = fdec(gmax[g * 256 + threadIdx.x]);
  __syncthreads();
  float acc = bc1[c];
#pragma unroll 16
  for (int k = 0; k < 256; ++k)
    acc = fmaf(g0[k], Wc1[(size_t)k * 1024 + c], acc);
  c1[g * 1024 + c] = fmaxf(acc, 0.f);
}

// ---------- MLP layer 2: c2raw[64][512] += c1@Wc2 (4-way K-split). 512 blocks ----------
__global__ __launch_bounds__(256) void mlp_l2(const float* __restrict__ c1,
                                              const float* __restrict__ Wc2,
                                              float* __restrict__ c2raw) {
  const int b = blockIdx.x;
  const int g = b >> 3;             // graph 0..63
  const int cc = (b >> 2) & 1;      // col chunk (2 × 256)
  const int kc = b & 3;             // k chunk (4 × 256)
  const int c = cc * 256 + threadIdx.x;
  __shared__ float h[256];
  h[threadIdx.x] = c1[g * 1024 + kc * 256 + threadIdx.x];
  __syncthreads();
  float acc = 0.f;
#pragma unroll 16
  for (int k = 0; k < 256; ++k)
    acc = fmaf(h[k], Wc2[(size_t)(kc * 256 + k) * 512 + c], acc);
  atomicAdd(&c2raw[g * 512 + c], acc);
}

// ---------- MLP layer 3: out[64][4] = relu(c2raw+bc2) @ Wc3 + bc3. 64 blocks ----------
__global__ __launch_bounds__(256) void mlp_l3(const float* __restrict__ c2raw,
                                              const float* __restrict__ bc2,
                                              const float* __restrict__ Wc3,
                                              const float* __restrict__ bc3,
                                              float* __restrict__ out) {
  __shared__ float red[256][4];
  const int m = blockIdx.x, t = threadIdx.x;
  float acc[4] = {0.f, 0.f, 0.f, 0.f};
  for (int k = t; k < 512; k += 256) {
    float hv = fmaxf(c2raw[m * 512 + k] + bc2[k], 0.f);
#pragma unroll
    for (int n = 0; n < 4; ++n) acc[n] = fmaf(hv, Wc3[k * 4 + n], acc[n]);
  }
#pragma unroll
  for (int n = 0; n < 4; ++n) red[t][n] = acc[n];
  __syncthreads();
  for (int s = 128; s > 0; s >>= 1) {
    if (t < s)
#pragma unroll
      for (int n = 0; n < 4; ++n) red[t][n] += red[t + s][n];
    __syncthreads();
  }
  if (t < 4) out[m * 4 + t] = red[0][t] + bc3[t];
}

extern "C" void kernel_launch(void* const* d_in, const int* in_sizes, int n_in,
                              void* d_out, int out_size, void* d_ws, size_t ws_size,
                              hipStream_t stream) {
  const float* x   = (const float*)d_in[0];
  const int*   ei  = (const int*)d_in[1];
  const int* batch = (const int*)d_in[2];
  const float* W1  = (const float*)d_in[3];
  const float* b1  = (const float*)d_in[4];
  const float* W2  = (const float*)d_in[5];
  const float* b2  = (const float*)d_in[6];
  const float* W3  = (const float*)d_in[7];
  const float* b3  = (const float*)d_in[8];
  const float* Wc1 = (const float*)d_in[9];
  const float* bc1 = (const float*)d_in[10];
  const float* Wc2 = (const float*)d_in[11];
  const float* bc2 = (const float*)d_in[12];
  const float* Wc3 = (const float*)d_in[13];
  const float* bc3 = (const float*)d_in[14];
  const int* src = ei;
  const int* dst = ei + NE;

  // ---- workspace layout (all starts 256B-aligned) ----
  char* base = (char*)d_ws;
  size_t off = 0;
  auto take = [&](size_t bytes) {
    size_t o = off;
    off += (bytes + 255) & ~(size_t)255;
    return o;
  };
  int*      deg_cnt   = (int*)(base + take((size_t)NN * 4));
  float*    dinv      = (float*)(base + take((size_t)NN * 4));
  int*      row_start = (int*)(base + take((size_t)(NN + 1) * 4));
  int*      cursor    = (int*)(base + take((size_t)NN * 4));
  int*      partials  = (int*)(base + take((size_t)SCAN_NB * 4));
  int*      csr       = (int*)(base + take((size_t)NE * 4));
  unsigned* gmax      = (unsigned*)(base + take((size_t)NG * 256 * 4));
  float*    c1buf     = (float*)(base + take((size_t)NG * 1024 * 4));
  float*    c2raw     = (float*)(base + take((size_t)NG * 512 * 4));
  // big buffers; keep B64_a,B64_b,B128_a contiguous: out3 (51.2MB) overlays them
  float* B64_a  = (float*)(base + take((size_t)NN * 64 * 4));   // hs0, then a2
  float* B64_b  = (float*)(base + take((size_t)NN * 64 * 4));   // hs1
  float* B128_a = (float*)(base + take((size_t)NN * 128 * 4));  // hs2
  float* B128_b = (float*)(base + take((size_t)NN * 128 * 4));  // a3
  float* out3   = B64_a;  // spans B64_a..B128_a end exactly (12.8+12.8+25.6 = 51.2MB)

  // ---- graph build ----
  hipMemsetAsync(deg_cnt, 0, (size_t)NN * 4, stream);
  hipMemsetAsync(gmax, 0, (size_t)NG * 256 * 4, stream);  // 0 == encoded "below any float"
  hipMemsetAsync(c2raw, 0, (size_t)NG * 512 * 4, stream);
  hist_kernel<<<(NE + 255) / 256, 256, 0, stream>>>(dst, deg_cnt);
  scan_reduce<<<SCAN_NB, 256, 0, stream>>>(deg_cnt, partials);
  scan_partials<<<1, 128, 0, stream>>>(partials);
  scan_write<<<SCAN_NB, 256, 0, stream>>>(deg_cnt, partials, row_start, cursor, dinv);
  scatter_kernel<<<(NE + 255) / 256, 256, 0, stream>>>(src, dst, cursor, csr);

  const int gy = (NN + 127) / 128;  // 391

  // ---- conv1: hs0 = dinv*(x@W1) ; hs1 = dinv*leaky(Ahat+b1) ----
  gemm_big<64, 0><<<dim3(1, gy), 256, 0, stream>>>(x, W1, nullptr, dinv, B64_a, NN, 64, 128);
  agg64_kernel<1><<<(NN * 64) / 256, 256, 0, stream>>>(B64_a, dinv, row_start, csr, b1, B64_b);

  // ---- conv2: a2 = Ahat(out1) (from hs1) ; hs2 = dinv*leaky(a2@W2+b2) ----
  agg64_kernel<0><<<(NN * 64) / 256, 256, 0, stream>>>(B64_b, dinv, row_start, csr, nullptr, B64_a);
  gemm_big<128, 1><<<dim3(1, gy), 256, 0, stream>>>(B64_a, W2, b2, dinv, B128_a, NN, 128, 64);

  // ---- conv3: a3 = Ahat(out2) (from hs2) ; out3 = a3@W3+b3 ----
  agg128_kernel<<<(NN * 64) / 256, 256, 0, stream>>>(B128_a, dinv, row_start, csr, B128_b);
  gemm_big<128, 2><<<dim3(2, gy), 256, 0, stream>>>(B128_b, W3, b3, nullptr, out3, NN, 256, 128);

  // ---- pooling + MLP (3 thin high-parallelism kernels) ----
  segmax_kernel<<<(NN + SEG_CHUNK - 1) / SEG_CHUNK, 256, 0, stream>>>(out3, batch, gmax);
  mlp_l1<<<NG * 4, 256, 0, stream>>>(gmax, Wc1, bc1, c1buf);
  mlp_l2<<<NG * 8, 256, 0, stream>>>(c1buf, Wc2, c2raw);
  mlp_l3<<<NG, 256, 0, stream>>>(c2raw, bc2, Wc3, bc3, (float*)d_out);
}